// Round 28
// baseline (96.368 us; speedup 1.0000x reference)
//
#include <hip/hip_runtime.h>

#define HW 128
#define XBB 2304         // byte offset of x double-buffer (after SoA ktab)
#define LDS_BYTES 10016  // 2304 + 2*3840 + 32 pad (masked tail reads)

typedef __attribute__((ext_vector_type(8))) short  bfrag;   // 8 bf16
typedef __attribute__((ext_vector_type(16))) float f16x;    // 32x32 accumulator
typedef __attribute__((ext_vector_type(4)))  float f4;

__device__ __forceinline__ float lrelu(float x) { return x > 0.f ? x : 0.1f * x; }

// RNE fp32 -> bf16
__device__ __forceinline__ short f2bf(float f) {
    unsigned u = __builtin_bit_cast(unsigned, f);
    u = u + 0x7FFFu + ((u >> 16) & 1u);
    return (short)(u >> 16);
}

// SoA per batch: [0..255] kf0 (row*4+tp0..3) | [256..511] kf1 (tp4..7) | [512..575] k8
__device__ float g_ktab[32 * 768];
__device__ short g_whi[4096];                     // conv_w bf16 (RNE), [o*64+c]

// ---------- prep: b<32 -> att-folded kernels (SoA); b==32 -> W bf16 ----------
__global__ __launch_bounds__(64) void dgfem_prep(
    const float* __restrict__ v, const float* __restrict__ ca_w1,
    const float* __restrict__ ca_w2, const float* __restrict__ k_w1,
    const float* __restrict__ k_w2, const float* __restrict__ conv_w)
{
    const int b = blockIdx.x;
    const int t = threadIdx.x;           // 64 threads

    if (b == 32) {
        for (int i = t; i < 4096; i += 64) g_whi[i] = f2bf(conv_w[i]);
        return;
    }

    __shared__ float vb[64], t1[8], att[64], t2[64];
    vb[t] = v[b * 64 + t];
    __syncthreads();

    if (t < 8) {
        float s = 0.f;
        for (int j = 0; j < 64; ++j) s += vb[j] * ca_w1[t * 64 + j];
        t1[t] = lrelu(s);
    }
    {
        float s = 0.f;
        for (int j = 0; j < 64; ++j) s += vb[j] * k_w1[t * 64 + j];
        t2[t] = lrelu(s);
    }
    __syncthreads();
    {
        float s = 0.f;
        for (int i = 0; i < 8; ++i) s += t1[i] * ca_w2[t * 8 + i];
        att[t] = 1.f / (1.f + expf(-s));
    }
    __syncthreads();
    // fold att[c]; SoA layout, row = ((m*2+a)*2+g)*4+j2, c = m*16+g*8+a*4+j2
    for (int r = t; r < 576; r += 64) {
        int c = r / 9, tp = r - c * 9;
        float s = 0.f;
        for (int j = 0; j < 64; ++j) s += t2[j] * k_w2[r * 64 + j];
        int m = c >> 4, g = (c >> 3) & 1, a = (c >> 2) & 1, j2 = c & 3;
        int row = ((m * 2 + a) * 2 + g) * 4 + j2;
        int dst = (tp < 4) ? (row * 4 + tp)
                : (tp < 8) ? (256 + row * 4 + (tp - 4))
                           : (512 + row);
        g_ktab[b * 768 + dst] = s * att[c];
    }
}

// ---- 1-wave workgroups: wave-private staging, pure-stage vmcnt ledger, 0 barriers ----
__global__ __launch_bounds__(64) void dgfem_main(
    const float* __restrict__ x0, const float* __restrict__ conv_b,
    float* __restrict__ out)
{
    const int l  = threadIdx.x;          // one wave per block
    const int g  = l >> 5;               // k-half
    const int ln = l & 31;

    // XCD swizzle (16384 % 8 == 0, bijective)
    const int bid  = blockIdx.x;
    const int orig = (bid & 7) * 2048 + (bid >> 3);
    const int b    = orig >> 9;          // 0..31
    const int rem  = orig & 511;
    const int gy   = rem >> 2;           // output row
    const int px0  = (rem & 3) * 32;     // this wave's px tile
    const int px   = px0 + ln;

    __shared__ __align__(16) char lds[LDS_BYTES];
    float* ldsf = (float*)lds;

    // stage SoA ktab with row masks folded in (same-wave: no barrier needed)
    {
        const float* ksrc = g_ktab + b * 768;
        const float rm0 = (gy > 0)   ? 1.f : 0.f;
        const float rm2 = (gy < 127) ? 1.f : 0.f;
        for (int i = l; i < 576; i += 64) {
            float rm;
            if (i < 256)      rm = ((i & 3) < 3) ? rm0 : 1.f;
            else if (i < 512) rm = ((i & 3) < 2) ? 1.f : rm2;
            else              rm = rm2;
            ldsf[i] = ksrc[i] * rm;
        }
    }

    // block-uniform staged window: bytes [ws, ws+160) of each row (always in-row)
    const int ws  = min(max(px0 * 4 - 16, 0), 352);
    const int ADJ = px0 - (ws >> 2) - 1;             // consume index shift

    // per-lane staging source offsets; LDS slot ch holds channel base+(ch>>2)*8+(ch&3)
    int s0, s1, s2, s3, s4, s5;
    {
        #pragma unroll
        for (int q = 0; q < 6; ++q) {
            int F     = (q < 3) ? (q * 1024 + l * 16) : (3072 + (q - 3) * 256 + l * 4);
            int ch    = F / 480, wq = F - ch * 480;
            int chsrc = (ch >> 2) * 8 + (ch & 3);    // gather: slot -> channel
            int row   = wq / 160, colb = wq - row * 160;
            int crow  = min(max(gy - 1 + row, 0), 127);
            int iv    = chsrc * 65536 + crow * 512 + ws + colb;
            if (q == 0) s0 = iv; else if (q == 1) s1 = iv; else if (q == 2) s2 = iv;
            else if (q == 3) s3 = iv; else if (q == 4) s4 = iv; else s5 = iv;
        }
    }

    const char* xb = (const char*)x0 + ((size_t)b << 22);

    // stage 8 channels x 3 rows x 40 floats; 3x width16 + 3x width4 (no row crossings)
    #define STAGE(rr_, sel_)                                                   \
    {                                                                          \
        const char* srcb = xb + ((size_t)(((rr_) >> 1) * 16 + ((rr_) & 1) * 4) << 16); \
        char* dstb = lds + XBB + (sel_) * 3840;                                \
        __builtin_amdgcn_global_load_lds(                                      \
            (const __attribute__((address_space(1))) unsigned*)(srcb + s0),    \
            (__attribute__((address_space(3))) unsigned*)(dstb), 16, 0, 0);    \
        __builtin_amdgcn_global_load_lds(                                      \
            (const __attribute__((address_space(1))) unsigned*)(srcb + s1),    \
            (__attribute__((address_space(3))) unsigned*)(dstb + 1024), 16, 0, 0); \
        __builtin_amdgcn_global_load_lds(                                      \
            (const __attribute__((address_space(1))) unsigned*)(srcb + s2),    \
            (__attribute__((address_space(3))) unsigned*)(dstb + 2048), 16, 0, 0); \
        __builtin_amdgcn_global_load_lds(                                      \
            (const __attribute__((address_space(1))) unsigned*)(srcb + s3),    \
            (__attribute__((address_space(3))) unsigned*)(dstb + 3072), 4, 0, 0); \
        __builtin_amdgcn_global_load_lds(                                      \
            (const __attribute__((address_space(1))) unsigned*)(srcb + s4),    \
            (__attribute__((address_space(3))) unsigned*)(dstb + 3328), 4, 0, 0); \
        __builtin_amdgcn_global_load_lds(                                      \
            (const __attribute__((address_space(1))) unsigned*)(srcb + s5),    \
            (__attribute__((address_space(3))) unsigned*)(dstb + 3584), 4, 0, 0); \
    }

    f16x acc0, acc1;
    #pragma unroll
    for (int i = 0; i < 16; ++i) { acc0[i] = 0.f; acc1[i] = 0.f; }

    const float mLf = (px > 0)   ? 1.f : 0.f;
    const float mRf = (px < 127) ? 1.f : 0.f;

    bfrag yh;

    // ---- prologue: ALL W fragments first (regular loads, retired before round 0's
    // wait), fenced so the compiler cannot sink them into the loop; then stage 0.
    bfrag wh0[4], wh1[4];
    {
        const char* wbase = (const char*)g_whi + ln * 128 + g * 16;
        #pragma unroll
        for (int m = 0; m < 4; ++m) {
            wh0[m] = *(const bfrag*)(wbase + m * 32);
            wh1[m] = *(const bfrag*)(wbase + m * 32 + 4096);
        }
    }
    __builtin_amdgcn_sched_barrier(0);
    STAGE(0, 0);

    // ROUND rr: STAGE(rr+1) -> vmcnt(6) [in-loop vmem is ONLY stage ops] ->
    // consume buf rr&1 -> [odd: MFMA]. No s_barrier anywhere.
    #define ROUND(rr_, a_, m_, sel_)                                           \
    {                                                                          \
        if ((rr_) < 7) {                                                       \
            STAGE((rr_) + 1, (sel_) ^ 1);                                      \
            asm volatile("s_waitcnt vmcnt(6)" ::: "memory");                   \
        } else {                                                               \
            asm volatile("s_waitcnt vmcnt(0)" ::: "memory");                   \
        }                                                                      \
        __builtin_amdgcn_sched_barrier(0);                                     \
        const float* xbase = ldsf + (576 + (sel_) * 960 + g * 480 + ln + ADJ); \
        const int    krowb = ((rr_) * 2 + g) * 4;                              \
        _Pragma("unroll")                                                      \
        for (int j2 = 0; j2 < 4; ++j2) {                                       \
            f4 kA = *(const f4*)(lds + (krowb + j2) * 16);                     \
            f4 kB = *(const f4*)(lds + 1024 + (krowb + j2) * 16);              \
            float k8v = *(const float*)(lds + 2048 + (krowb + j2) * 4);        \
            const float* bA = xbase + j2 * 120;                                \
            float xL0 = bA[0]  * mLf, xC0 = bA[1],  xR0 = bA[2]  * mRf;        \
            float xL1 = bA[40] * mLf, xC1 = bA[41], xR1 = bA[42] * mRf;        \
            float xL2 = bA[80] * mLf, xC2 = bA[81], xR2 = bA[82] * mRf;        \
            float aY = fmaf(kA.x, xL0, fmaf(kA.y, xC0, kA.z * xR0))            \
                     + fmaf(kA.w, xL1, fmaf(kB.x, xC1, kB.y * xR1))            \
                     + fmaf(kB.z, xL2, fmaf(kB.w, xC2, k8v  * xR2));           \
            yh[(a_) * 4 + j2] = f2bf(lrelu(aY));                               \
        }                                                                      \
        if (a_) {                                                              \
            acc0 = __builtin_amdgcn_mfma_f32_32x32x16_bf16(wh0[m_], yh, acc0, 0, 0, 0); \
            acc1 = __builtin_amdgcn_mfma_f32_32x32x16_bf16(wh1[m_], yh, acc1, 0, 0, 0); \
        }                                                                      \
    }

    ROUND(0, 0, 0, 0);
    ROUND(1, 1, 0, 1);
    ROUND(2, 0, 1, 0);
    ROUND(3, 1, 1, 1);
    ROUND(4, 0, 2, 0);
    ROUND(5, 1, 2, 1);
    ROUND(6, 0, 3, 0);
    ROUND(7, 1, 3, 1);

    #undef ROUND
    #undef STAGE

    // epilogue: D layout col=lane&31, row=(reg&3)+8*(reg>>2)+4*(lane>>5)  [verified 12x]
    float* ob = out + ((size_t)b << 20) + (size_t)gy * HW + px;
    #pragma unroll
    for (int q = 0; q < 4; ++q) {
        const int obase = 8 * q + 4 * g;
        float4 bv0 = *(const float4*)&conv_b[obase];
        float4 bv1 = *(const float4*)&conv_b[32 + obase];
        const float* b0f = (const float*)&bv0;
        const float* b1f = (const float*)&bv1;
        #pragma unroll
        for (int r2 = 0; r2 < 4; ++r2) {
            ob[(size_t)(obase + r2) * 16384]      = acc0[q * 4 + r2] + b0f[r2];
            ob[(size_t)(32 + obase + r2) * 16384] = acc1[q * 4 + r2] + b1f[r2];
        }
    }
}

extern "C" void kernel_launch(void* const* d_in, const int* in_sizes, int n_in,
                              void* d_out, int out_size, void* d_ws, size_t ws_size,
                              hipStream_t stream) {
    const float* x0     = (const float*)d_in[0];
    const float* v      = (const float*)d_in[1];
    const float* ca_w1  = (const float*)d_in[2];
    const float* ca_w2  = (const float*)d_in[3];
    const float* k_w1   = (const float*)d_in[4];
    const float* k_w2   = (const float*)d_in[5];
    const float* conv_w = (const float*)d_in[6];
    const float* conv_b = (const float*)d_in[7];
    float* outp = (float*)d_out;

    dgfem_prep<<<dim3(33), dim3(64), 0, stream>>>(v, ca_w1, ca_w2, k_w1, k_w2, conv_w);
    dgfem_main<<<dim3(16384), dim3(64), 0, stream>>>(x0, conv_b, outp);
}

// Round 29
// 85.436 us; speedup vs baseline: 1.1280x; 1.1280x over previous
//
#include <hip/hip_runtime.h>

#define HW 128
#define XBb 16           // byte offset of x TRIPLE-buffer (16B pad before)
#define XBf 4            // same, in floats
#define KTb 36880        // byte offset of SoA ktab = 16 + 3*12288
#define LDS_BYTES 39184  // 36880 + 2304

typedef __attribute__((ext_vector_type(8))) short  bfrag;   // 8 bf16
typedef __attribute__((ext_vector_type(16))) float f16x;    // 32x32 accumulator
typedef __attribute__((ext_vector_type(4)))  float f4;

__device__ __forceinline__ float lrelu(float x) { return x > 0.f ? x : 0.1f * x; }

// RNE fp32 -> bf16
__device__ __forceinline__ short f2bf(float f) {
    unsigned u = __builtin_bit_cast(unsigned, f);
    u = u + 0x7FFFu + ((u >> 16) & 1u);
    return (short)(u >> 16);
}

// SoA per batch: [0..255] kf0 (row*4+tp0..3) | [256..511] kf1 (tp4..7) | [512..575] k8
__device__ float g_ktab[32 * 768];
__device__ short g_whi[4096];                     // conv_w bf16 (RNE), [o*64+c]

// ---------- prep: b<32 -> att-folded kernels (SoA); b==32 -> W bf16 ----------
__global__ __launch_bounds__(64) void dgfem_prep(
    const float* __restrict__ v, const float* __restrict__ ca_w1,
    const float* __restrict__ ca_w2, const float* __restrict__ k_w1,
    const float* __restrict__ k_w2, const float* __restrict__ conv_w)
{
    const int b = blockIdx.x;
    const int t = threadIdx.x;           // 64 threads

    if (b == 32) {
        for (int i = t; i < 4096; i += 64) g_whi[i] = f2bf(conv_w[i]);
        return;
    }

    __shared__ float vb[64], t1[8], att[64], t2[64];
    vb[t] = v[b * 64 + t];
    __syncthreads();

    if (t < 8) {
        float s = 0.f;
        for (int j = 0; j < 64; ++j) s += vb[j] * ca_w1[t * 64 + j];
        t1[t] = lrelu(s);
    }
    {
        float s = 0.f;
        for (int j = 0; j < 64; ++j) s += vb[j] * k_w1[t * 64 + j];
        t2[t] = lrelu(s);
    }
    __syncthreads();
    {
        float s = 0.f;
        for (int i = 0; i < 8; ++i) s += t1[i] * ca_w2[t * 8 + i];
        att[t] = 1.f / (1.f + expf(-s));
    }
    __syncthreads();
    // fold att[c]; SoA layout, row = ((m*2+a)*2+g)*4+j2, c = m*16+g*8+a*4+j2
    for (int r = t; r < 576; r += 64) {
        int c = r / 9, tp = r - c * 9;
        float s = 0.f;
        for (int j = 0; j < 64; ++j) s += t2[j] * k_w2[r * 64 + j];
        int m = c >> 4, g = (c >> 3) & 1, a = (c >> 2) & 1, j2 = c & 3;
        int row = ((m * 2 + a) * 2 + g) * 4 + j2;
        int dst = (tp < 4) ? (row * 4 + tp)
                : (tp < 8) ? (256 + row * 4 + (tp - 4))
                           : (512 + row);
        g_ktab[b * 768 + dst] = s * att[c];
    }
}

__global__ __launch_bounds__(256) void dgfem_main(
    const float* __restrict__ x0, const float* __restrict__ conv_b,
    float* __restrict__ out)
{
    const int t  = threadIdx.x;          // 256 threads = 4 waves
    const int w  = t >> 6;
    const int l  = t & 63;
    const int g  = l >> 5;               // k-half
    const int ln = l & 31;
    const int px = w * 32 + ln;

    // XCD swizzle (4096 % 8 == 0, bijective)
    const int bid  = blockIdx.x;
    const int orig = (bid & 7) * 512 + (bid >> 3);
    const int b    = orig >> 7;          // 0..31
    const int gy   = orig & 127;         // output row

    __shared__ __align__(16) char lds[LDS_BYTES];
    float* ldsf = (float*)lds;

    // stage SoA ktab with row masks folded in (masked row taps -> 0)
    {
        const float* ksrc = g_ktab + b * 768;
        const float rm0 = (gy > 0)   ? 1.f : 0.f;
        const float rm2 = (gy < 127) ? 1.f : 0.f;
        for (int i = t; i < 576; i += 256) {
            float rm;
            if (i < 256)      rm = ((i & 3) < 3) ? rm0 : 1.f;
            else if (i < 512) rm = ((i & 3) < 2) ? 1.f : rm2;
            else              rm = rm2;
            *(float*)(lds + KTb + i * 4) = ksrc[i] * rm;
        }
    }

    // per-lane clamped source offsets: 3 sweeps of 1 KB per wave cover 12 KB/round
    const int doff = w * 1024 + l * 16;
    int inv0, inv1, inv2;
    {
        #pragma unroll
        for (int q = 0; q < 3; ++q) {
            int F      = q * 4096 + doff;
            int slot   = F / 1536;
            int within = F - slot * 1536;
            int rowq   = gy - 1 + (within >> 9);
            int crow   = min(max(rowq, 0), 127);
            int gs = slot >> 2, j2s = slot & 3;
            int iv = (gs * 8 + j2s) * 65536 + crow * 512 + (within & 511);
            if (q == 0) inv0 = iv; else if (q == 1) inv1 = iv; else inv2 = iv;
        }
    }

    const char* xb = (const char*)x0 + ((size_t)b << 22);

    // stage 8 channels x 3 row-slots into TRIPLE buffer s3
    #define STAGE(rr_, s3_)                                                    \
    {                                                                          \
        const char* srcb = xb + ((size_t)(((rr_) >> 1) * 16 + ((rr_) & 1) * 4) << 16); \
        char* dstb = lds + XBb + (s3_) * 12288 + doff;                         \
        __builtin_amdgcn_global_load_lds(                                      \
            (const __attribute__((address_space(1))) unsigned*)(srcb + inv0),  \
            (__attribute__((address_space(3))) unsigned*)(dstb), 16, 0, 0);    \
        __builtin_amdgcn_global_load_lds(                                      \
            (const __attribute__((address_space(1))) unsigned*)(srcb + inv1),  \
            (__attribute__((address_space(3))) unsigned*)(dstb + 4096), 16, 0, 0); \
        __builtin_amdgcn_global_load_lds(                                      \
            (const __attribute__((address_space(1))) unsigned*)(srcb + inv2),  \
            (__attribute__((address_space(3))) unsigned*)(dstb + 8192), 16, 0, 0); \
    }

    f16x acc0, acc1;
    #pragma unroll
    for (int i = 0; i < 16; ++i) { acc0[i] = 0.f; acc1[i] = 0.f; }

    const float mLf = (px > 0)   ? 1.f : 0.f;
    const float mRf = (px < 127) ? 1.f : 0.f;

    bfrag yh;
    bfrag whi0, whi1;                    // W pair for the CURRENT (even,odd) rounds
    const char* const wbase = (const char*)g_whi + ln * 128 + g * 16;

    // prologue: stage 0 and 1; retire stage0 (vmcnt(3)=stage1 still flying),
    // drain ktab ds_writes, then block-wide barrier.
    STAGE(0, 0);
    STAGE(1, 1);
    __builtin_amdgcn_sched_barrier(0);
    asm volatile("s_waitcnt vmcnt(3) lgkmcnt(0)" ::: "memory");
    __builtin_amdgcn_s_barrier();
    __builtin_amdgcn_sched_barrier(0);

    // ROUND rr: [even: W pair] -> STAGE(rr+2) -> consume buf[rr%3] -> [odd: MFMA]
    // -> retire-through stage(rr+1) (counted vmcnt) -> s_barrier.
    // Ledger (in-order vmem): end of round rr queue = stage(rr+1)[3]
    //  (+W[2] issued this round if even) + stage(rr+2)[3] -> B = 5 even / 3 odd;
    //  rr=6: queue = stage7[3]+W[2], retire stage7 -> B=2.
    #define ROUND(rr_, a_, m_, sel_, stg_, B_)                                 \
    {                                                                          \
        if (!(a_)) {                                                           \
            whi0 = *(const bfrag*)(wbase + (m_) * 32);                         \
            whi1 = *(const bfrag*)(wbase + (m_) * 32 + 4096);                  \
        }                                                                      \
        if ((rr_) < 6) STAGE((rr_) + 2, stg_);                                 \
        const float* xbase = ldsf + (XBf + (sel_) * 3072 + g * 1536 + px - 1); \
        const int    krowb = ((rr_) * 2 + g) * 4;                              \
        _Pragma("unroll")                                                      \
        for (int j2 = 0; j2 < 4; ++j2) {                                       \
            f4 kA = *(const f4*)(lds + KTb + (krowb + j2) * 16);               \
            f4 kB = *(const f4*)(lds + KTb + 1024 + (krowb + j2) * 16);        \
            float k8v = *(const float*)(lds + KTb + 2048 + (krowb + j2) * 4);  \
            const float* bA = xbase + j2 * 384;                                \
            float xL0 = bA[0]   * mLf, xC0 = bA[1],   xR0 = bA[2]   * mRf;     \
            float xL1 = bA[128] * mLf, xC1 = bA[129], xR1 = bA[130] * mRf;     \
            float xL2 = bA[256] * mLf, xC2 = bA[257], xR2 = bA[258] * mRf;     \
            float aY = fmaf(kA.x, xL0, fmaf(kA.y, xC0, kA.z * xR0))            \
                     + fmaf(kA.w, xL1, fmaf(kB.x, xC1, kB.y * xR1))            \
                     + fmaf(kB.z, xL2, fmaf(kB.w, xC2, k8v  * xR2));           \
            yh[(a_) * 4 + j2] = f2bf(lrelu(aY));                               \
        }                                                                      \
        if (a_) {                                                              \
            acc0 = __builtin_amdgcn_mfma_f32_32x32x16_bf16(whi0, yh, acc0, 0, 0, 0); \
            acc1 = __builtin_amdgcn_mfma_f32_32x32x16_bf16(whi1, yh, acc1, 0, 0, 0); \
        }                                                                      \
        if ((rr_) < 7) {                                                       \
            __builtin_amdgcn_sched_barrier(0);                                 \
            asm volatile("s_waitcnt vmcnt(" #B_ ")" ::: "memory");             \
            __builtin_amdgcn_s_barrier();                                      \
            __builtin_amdgcn_sched_barrier(0);                                 \
        }                                                                      \
    }

    ROUND(0, 0, 0, 0, 2, 5);
    ROUND(1, 1, 0, 1, 0, 3);
    ROUND(2, 0, 1, 2, 1, 5);
    ROUND(3, 1, 1, 0, 2, 3);
    ROUND(4, 0, 2, 1, 0, 5);
    ROUND(5, 1, 2, 2, 1, 3);
    ROUND(6, 0, 3, 0, 0, 2);
    ROUND(7, 1, 3, 1, 0, 0);

    #undef ROUND
    #undef STAGE

    // epilogue: D layout col=lane&31, row=(reg&3)+8*(reg>>2)+4*(lane>>5)  [verified 13x]
    float* ob = out + ((size_t)b << 20) + (size_t)gy * HW + px;
    #pragma unroll
    for (int q = 0; q < 4; ++q) {
        const int obase = 8 * q + 4 * g;
        float4 bv0 = *(const float4*)&conv_b[obase];
        float4 bv1 = *(const float4*)&conv_b[32 + obase];
        const float* b0f = (const float*)&bv0;
        const float* b1f = (const float*)&bv1;
        #pragma unroll
        for (int r2 = 0; r2 < 4; ++r2) {
            ob[(size_t)(obase + r2) * 16384]      = acc0[q * 4 + r2] + b0f[r2];
            ob[(size_t)(32 + obase + r2) * 16384] = acc1[q * 4 + r2] + b1f[r2];
        }
    }
}

extern "C" void kernel_launch(void* const* d_in, const int* in_sizes, int n_in,
                              void* d_out, int out_size, void* d_ws, size_t ws_size,
                              hipStream_t stream) {
    const float* x0     = (const float*)d_in[0];
    const float* v      = (const float*)d_in[1];
    const float* ca_w1  = (const float*)d_in[2];
    const float* ca_w2  = (const float*)d_in[3];
    const float* k_w1   = (const float*)d_in[4];
    const float* k_w2   = (const float*)d_in[5];
    const float* conv_w = (const float*)d_in[6];
    const float* conv_b = (const float*)d_in[7];
    float* outp = (float*)d_out;

    dgfem_prep<<<dim3(33), dim3(64), 0, stream>>>(v, ca_w1, ca_w2, k_w1, k_w2, conv_w);
    dgfem_main<<<dim3(4096), dim3(256), 0, stream>>>(x0, conv_b, outp);
}